// Round 11
// baseline (385.219 us; speedup 1.0000x reference)
//
#include <hip/hip_runtime.h>

namespace {
constexpr int kB = 32, kT = 30, kD = 512, kL = 196;
constexpr float kK = 2.8853900817779268f;  // 2*log2(e)
constexpr size_t kEgN = (size_t)kB * kT * kD;      // 491,520
constexpr size_t kFN = (size_t)kB * 128 * kL * 4;  // 3,211,264
constexpr size_t kGsz = (size_t)kB * kT * kL;      // 188,160

// vwi/u + vwj/v = (vwi*v + vwj*u) * rcp(u*v): 1 rcp per 2 elements
#define PAIR(ex, ey, fx, fy, vx, vy, acc)                                   \
  {                                                                         \
    const float u_ = fmaf(ex, fx, 1.f);                                     \
    const float v_ = fmaf(ey, fy, 1.f);                                     \
    acc = fmaf(fmaf(v_, vx, u_ * vy), __builtin_amdgcn_rcpf(u_ * v_), acc); \
  }

// INSTRUMENTED ROUND: each kernel repeats its (idempotent) body `rep` times.
// The empty asm with a memory clobber stops the compiler from hoisting the
// loads / collapsing the loop. Per-kernel time = dispatch_dur / rep.

// Fused prep: blocks [0,120) -> Eg = 2^(kK(x+w)); [120,568) -> imgF4 transpose-exp.
__global__ __launch_bounds__(256) void k_prep(const float* __restrict__ x,
                                              const float* __restrict__ w,
                                              const float* __restrict__ img,
                                              float* __restrict__ Eg,
                                              float* __restrict__ imgF4,
                                              int rep) {
  const int bx = blockIdx.x;
  for (int r = 0; r < rep; ++r) {
    asm volatile("" ::: "memory");
    if (bx < 120) {
      const float4* x4 = (const float4*)x;
      const float4* w4 = (const float4*)w;
      float4* e4 = (float4*)Eg;
#pragma unroll
      for (int k = 0; k < 4; ++k) {
        const int i = bx * 256 + threadIdx.x + k * 120 * 256;
        const float4 a = x4[i], b = w4[i];
        float4 rr;
        rr.x = __builtin_amdgcn_exp2f(kK * (a.x + b.x));
        rr.y = __builtin_amdgcn_exp2f(kK * (a.y + b.y));
        rr.z = __builtin_amdgcn_exp2f(kK * (a.z + b.z));
        rr.w = __builtin_amdgcn_exp2f(kK * (a.w + b.w));
        e4[i] = rr;
      }
    } else {
      const int n = bx - 120;  // 448 = 14 lq x 32 b
      const int lq = n % 14, b = n / 14;
      const int tid = threadIdx.x;
      const int ls = tid >> 7, dq = tid & 127;
#pragma unroll
      for (int q = 0; q < 7; ++q) {
        const int l = lq * 14 + 2 * q + ls;
        const float4 v =
            *(const float4*)(img + ((size_t)(b * kL + l)) * kD + 4 * dq);
        float4 o;
        o.x = __builtin_amdgcn_exp2f(kK * v.x);
        o.y = __builtin_amdgcn_exp2f(kK * v.y);
        o.z = __builtin_amdgcn_exp2f(kK * v.z);
        o.w = __builtin_amdgcn_exp2f(kK * v.w);
        *(float4*)(imgF4 + (((size_t)(b * 128 + dq)) * kL + l) * 4) = o;
      }
    }
  }
}

// g8[dq][b][t][l] (l<192) = sum over 64 d of vw_d/(1+E*F).
// 6144 one-wave blocks; XCD b-affinity. Wave = 4t x 64l x 64d.
// E/vw wave-uniform -> s_load (lgkm path, separate from F's vmcnt).
__global__ __launch_bounds__(64) void k_scoreT(const float* __restrict__ Eg,
                                               const float* __restrict__ imgF4,
                                               const float* __restrict__ vw,
                                               float* __restrict__ g8,
                                               int rep) {
  const int lane = threadIdx.x;
  int n = blockIdx.x;
  const int bg = n & 7;
  int m = n >> 3;  // 768 = 4 bi * 3 lc * 8 tq * 8 dq
  const int bi = m & 3; m >>= 2;
  const int lc = m % 3; m /= 3;
  const int tq = m & 7;
  const int dq = m >> 3;
  const int b = bg * 4 + bi;
  const int t0 = (tq < 7) ? tq * 4 : 26;  // rows 26,27 dup'd (bit-identical)
  for (int r = 0; r < rep; ++r) {
    asm volatile("" ::: "memory");
    const float* Fp =
        imgF4 + (((size_t)(b * 128 + dq * 16)) * kL + lc * 64 + lane) * 4;
    const float* e0 = Eg + ((size_t)(b * kT + t0)) * kD + dq * 64;
    const float* e1 = e0 + kD;
    const float* e2 = e0 + 2 * kD;
    const float* e3 = e0 + 3 * kD;
    const float* vp = vw + dq * 64;
    float a0 = 0.f, a1 = 0.f, a2 = 0.f, a3 = 0.f;
    auto loadF = [&](float4* dst, int bb) {
#pragma unroll
      for (int j = 0; j < 8; ++j)
        dst[j] = *(const float4*)(Fp + (size_t)(bb * 8 + j) * (kL * 4));
    };
    auto compF = [&](const float4* f, int bb) {
#pragma unroll
      for (int j = 0; j < 8; ++j) {
        const int s = bb * 8 + j;
        const float4 vv = *(const float4*)(vp + 4 * s);  // uniform -> s_load
        const float4 E0 = *(const float4*)(e0 + 4 * s);  // uniform -> s_load
        const float4 E1 = *(const float4*)(e1 + 4 * s);
        const float4 E2 = *(const float4*)(e2 + 4 * s);
        const float4 E3 = *(const float4*)(e3 + 4 * s);
        PAIR(E0.x, E0.y, f[j].x, f[j].y, vv.x, vv.y, a0);
        PAIR(E0.z, E0.w, f[j].z, f[j].w, vv.z, vv.w, a0);
        PAIR(E1.x, E1.y, f[j].x, f[j].y, vv.x, vv.y, a1);
        PAIR(E1.z, E1.w, f[j].z, f[j].w, vv.z, vv.w, a1);
        PAIR(E2.x, E2.y, f[j].x, f[j].y, vv.x, vv.y, a2);
        PAIR(E2.z, E2.w, f[j].z, f[j].w, vv.z, vv.w, a2);
        PAIR(E3.x, E3.y, f[j].x, f[j].y, vv.x, vv.y, a3);
        PAIR(E3.z, E3.w, f[j].z, f[j].w, vv.z, vv.w, a3);
      }
    };
    float4 fA[8], fB[8];
    loadF(fA, 0);
    loadF(fB, 1);
    compF(fA, 0);
    compF(fB, 1);
    float* gp =
        g8 + (size_t)dq * kGsz + ((size_t)(b * kT + t0)) * kL + lc * 64 + lane;
    gp[0] = a0;
    gp[kL] = a1;
    gp[2 * kL] = a2;
    gp[3 * kL] = a3;
  }
}

// softmax over l: l<192 from 8 partials; l=192..195 computed inline (512 d)
__global__ __launch_bounds__(512) void k_alpha(const float* __restrict__ g8,
                                               const float* __restrict__ Eg,
                                               const float* __restrict__ img,
                                               const float* __restrict__ vw,
                                               float* __restrict__ alpha,
                                               int rep) {
  const int qd = blockIdx.x, b = blockIdx.y;
  const int lane = threadIdx.x & 63, wv = threadIdx.x >> 6;
  const int t = qd * 8 + wv;
  for (int r = 0; r < rep; ++r) {
    asm volatile("" ::: "memory");
    if (t >= kT) continue;
    const int l4 = lane & 3, dc = lane >> 2;
    const float* ir = img + ((size_t)(b * kL + 192 + l4)) * kD + dc * 32;
    const float* er = Eg + ((size_t)(b * kT + t)) * kD + dc * 32;
    const float* vr = vw + dc * 32;
    float tg = 0.f;
#pragma unroll
    for (int k = 0; k < 8; ++k) {
      const float4 iv = *(const float4*)(ir + 4 * k);
      const float4 ev = *(const float4*)(er + 4 * k);
      const float4 vv = *(const float4*)(vr + 4 * k);
      PAIR(ev.x, ev.y, __builtin_amdgcn_exp2f(kK * iv.x),
           __builtin_amdgcn_exp2f(kK * iv.y), vv.x, vv.y, tg);
      PAIR(ev.z, ev.w, __builtin_amdgcn_exp2f(kK * iv.z),
           __builtin_amdgcn_exp2f(kK * iv.w), vv.z, vv.w, tg);
    }
#pragma unroll
    for (int mm = 4; mm < 64; mm <<= 1) tg += __shfl_xor(tg, mm, 64);
    const size_t base = ((size_t)(b * kT + t)) * kL;
    float q0 = 0.f, q1 = 0.f, q2 = 0.f;
#pragma unroll
    for (int p = 0; p < 8; ++p) {
      const float* gp = g8 + (size_t)p * kGsz + base;
      q0 += gp[lane];
      q1 += gp[lane + 64];
      q2 += gp[lane + 128];
    }
    q0 *= kK; q1 *= kK; q2 *= kK;
    float q3 = (lane < 4) ? tg * kK : __builtin_inff();
    float m = fminf(fminf(q0, q1), fminf(q2, q3));
#pragma unroll
    for (int mm = 1; mm < 64; mm <<= 1) m = fminf(m, __shfl_xor(m, mm, 64));
    const float e0 = __builtin_amdgcn_exp2f(m - q0);
    const float e1 = __builtin_amdgcn_exp2f(m - q1);
    const float e2 = __builtin_amdgcn_exp2f(m - q2);
    const float e3 = (lane < 4) ? __builtin_amdgcn_exp2f(m - q3) : 0.f;
    float s = e0 + e1 + e2 + e3;
#pragma unroll
    for (int mm = 1; mm < 64; mm <<= 1) s += __shfl_xor(s, mm, 64);
    const float rs = __builtin_amdgcn_rcpf(s);
    float* ab = alpha + base;
    ab[lane] = e0 * rs;
    ab[lane + 64] = e1 * rs;
    ab[lane + 128] = e2 * rs;
    if (lane < 4) ab[lane + 192] = e3 * rs;
  }
}

// context[b][t][d] = sum_l img[b][l][d]*alpha[b][t][l].
// 384 blocks, XCD b-affinity; 4 waves own 49-l quarters; 8-deep img dbuf.
__global__ __launch_bounds__(256) void k_ctx(const float* __restrict__ img,
                                             const float* __restrict__ alpha,
                                             float* __restrict__ out,
                                             int rep) {
  __shared__ __align__(16) float red[4][5][256];  // 20 KB
  int n = blockIdx.x;
  const int bg = n & 7;
  int m = n >> 3;  // 48 = 4 bi * 6 tg * 2 dh
  const int bi = m & 3; m >>= 2;
  const int tg = m % 6;
  const int dh = m / 6;
  const int b = bg * 4 + bi;
  const int t0 = tg * 5, d0 = dh * 256;
  const int tid = threadIdx.x;
  const int lane = tid & 63;
  const int lru = __builtin_amdgcn_readfirstlane(tid >> 6);
  for (int r = 0; r < rep; ++r) {
    asm volatile("" ::: "memory");
    const float* ap = alpha + ((size_t)(b * kT + t0)) * kL + lru * 49;
    const float* ip = img + ((size_t)(b * kL + lru * 49)) * kD + d0 + 4 * lane;
    float4 acc[5];
#pragma unroll
    for (int j = 0; j < 5; ++j) acc[j] = {0.f, 0.f, 0.f, 0.f};
    auto loadI = [&](float4* dst, int bb) {
#pragma unroll
      for (int j = 0; j < 8; ++j)
        dst[j] = *(const float4*)(ip + (size_t)(bb * 8 + j) * kD);
    };
    auto compI = [&](const float4* f, int bb) {
#pragma unroll
      for (int j = 0; j < 8; ++j) {
        const int i = bb * 8 + j;
        const float a0 = ap[i];
        const float a1 = ap[kL + i];
        const float a2 = ap[2 * kL + i];
        const float a3 = ap[3 * kL + i];
        const float a4 = ap[4 * kL + i];
        acc[0].x = fmaf(f[j].x, a0, acc[0].x); acc[0].y = fmaf(f[j].y, a0, acc[0].y);
        acc[0].z = fmaf(f[j].z, a0, acc[0].z); acc[0].w = fmaf(f[j].w, a0, acc[0].w);
        acc[1].x = fmaf(f[j].x, a1, acc[1].x); acc[1].y = fmaf(f[j].y, a1, acc[1].y);
        acc[1].z = fmaf(f[j].z, a1, acc[1].z); acc[1].w = fmaf(f[j].w, a1, acc[1].w);
        acc[2].x = fmaf(f[j].x, a2, acc[2].x); acc[2].y = fmaf(f[j].y, a2, acc[2].y);
        acc[2].z = fmaf(f[j].z, a2, acc[2].z); acc[2].w = fmaf(f[j].w, a2, acc[2].w);
        acc[3].x = fmaf(f[j].x, a3, acc[3].x); acc[3].y = fmaf(f[j].y, a3, acc[3].y);
        acc[3].z = fmaf(f[j].z, a3, acc[3].z); acc[3].w = fmaf(f[j].w, a3, acc[3].w);
        acc[4].x = fmaf(f[j].x, a4, acc[4].x); acc[4].y = fmaf(f[j].y, a4, acc[4].y);
        acc[4].z = fmaf(f[j].z, a4, acc[4].z); acc[4].w = fmaf(f[j].w, a4, acc[4].w);
      }
    };
    float4 fA[8], fB[8];
    loadI(fA, 0);
    loadI(fB, 1); compI(fA, 0);
    loadI(fA, 2); compI(fB, 1);
    loadI(fB, 3); compI(fA, 2);
    loadI(fA, 4); compI(fB, 3);
    loadI(fB, 5); compI(fA, 4);
    compI(fB, 5);
    {  // tail l-index 48 of this quarter
      const float4 v = *(const float4*)(ip + (size_t)48 * kD);
      const int i = 48;
      const float a0 = ap[i], a1 = ap[kL + i], a2 = ap[2 * kL + i],
                  a3 = ap[3 * kL + i], a4 = ap[4 * kL + i];
      acc[0].x = fmaf(v.x, a0, acc[0].x); acc[0].y = fmaf(v.y, a0, acc[0].y);
      acc[0].z = fmaf(v.z, a0, acc[0].z); acc[0].w = fmaf(v.w, a0, acc[0].w);
      acc[1].x = fmaf(v.x, a1, acc[1].x); acc[1].y = fmaf(v.y, a1, acc[1].y);
      acc[1].z = fmaf(v.z, a1, acc[1].z); acc[1].w = fmaf(v.w, a1, acc[1].w);
      acc[2].x = fmaf(v.x, a2, acc[2].x); acc[2].y = fmaf(v.y, a2, acc[2].y);
      acc[2].z = fmaf(v.z, a2, acc[2].z); acc[2].w = fmaf(v.w, a2, acc[2].w);
      acc[3].x = fmaf(v.x, a3, acc[3].x); acc[3].y = fmaf(v.y, a3, acc[3].y);
      acc[3].z = fmaf(v.z, a3, acc[3].z); acc[3].w = fmaf(v.w, a3, acc[3].w);
      acc[4].x = fmaf(v.x, a4, acc[4].x); acc[4].y = fmaf(v.y, a4, acc[4].y);
      acc[4].z = fmaf(v.z, a4, acc[4].z); acc[4].w = fmaf(v.w, a4, acc[4].w);
    }
#pragma unroll
    for (int j = 0; j < 5; ++j) *(float4*)&red[lru][j][4 * lane] = acc[j];
    __syncthreads();
#pragma unroll
    for (int j = 0; j < 5; ++j) {
      const float s =
          red[0][j][tid] + red[1][j][tid] + red[2][j][tid] + red[3][j][tid];
      out[((size_t)(b * kT + t0 + j)) * kD + d0 + tid] = s;
    }
    __syncthreads();  // protect red[] from next iteration's writes
  }
}
}  // namespace

extern "C" void kernel_launch(void* const* d_in, const int* in_sizes, int n_in,
                              void* d_out, int out_size, void* d_ws, size_t ws_size,
                              hipStream_t stream) {
  const float* x = (const float*)d_in[0];
  const float* wordemb = (const float*)d_in[1];
  const float* img = (const float*)d_in[2];
  const float* vw = (const float*)d_in[3];
  // v_b (d_in[4]) cancels in the softmax along with sum(v_w) — unused by design.
  float* out = (float*)d_out;
  float* Eg = (float*)d_ws;      // 1.97 MB
  float* imgF4 = Eg + kEgN;      // 12.8 MB
  float* g8 = imgF4 + kFN;       // 6.02 MB
  float* alpha = g8 + 8 * kGsz;  // 0.75 MB
  // Instrumented: rep chosen so each dispatch exceeds the ~43us harness fills.
  hipLaunchKernelGGL(k_prep, dim3(568), dim3(256), 0, stream, x, wordemb, img,
                     Eg, imgF4, 16);
  hipLaunchKernelGGL(k_scoreT, dim3(6144), dim3(64), 0, stream, Eg, imgF4, vw,
                     g8, 8);
  hipLaunchKernelGGL(k_alpha, dim3(4, kB), dim3(512), 0, stream, g8, Eg, img,
                     vw, alpha, 48);
  hipLaunchKernelGGL(k_ctx, dim3(384), dim3(256), 0, stream, img, alpha, out,
                     16);
}

// Round 12
// 87.002 us; speedup vs baseline: 4.4277x; 4.4277x over previous
//
#include <hip/hip_runtime.h>

namespace {
constexpr int kB = 32, kT = 30, kD = 512, kL = 196;
constexpr float kK = 2.8853900817779268f;  // 2*log2(e)
constexpr size_t kGsz = (size_t)kB * kT * kL;  // 188,160

// vwi/u + vwj/v = (vwi*v + vwj*u) * rcp(u*v): 1 rcp per 2 elements
#define PAIR(ex, ey, fx, fy, vx, vy, acc)                                   \
  {                                                                         \
    const float u_ = fmaf(ex, fx, 1.f);                                     \
    const float v_ = fmaf(ey, fy, 1.f);                                     \
    acc = fmaf(fmaf(v_, vx, u_ * vy), __builtin_amdgcn_rcpf(u_ * v_), acc); \
  }

// g8[dqg][b][t][l] (l<192) = sum over 64 d of vw_d/(1+E*F).
// 768 blocks (bg:8 XCD-affine x bi:4 x lc:3 x dqg:8) x 512 thr (8 waves).
// E,F,vw staged in LDS once; inner loop: E/vw uniform broadcasts (free),
// F per-lane b128 (XOR-swizzled, conflict-free). No s_loads on hot path.
__global__ __launch_bounds__(512) void k_score(const float* __restrict__ x,
                                               const float* __restrict__ w,
                                               const float* __restrict__ img,
                                               const float* __restrict__ vw,
                                               float* __restrict__ g8) {
  __shared__ __align__(16) float4 Fl4[16 * 64];  // [c][l ^ (c&7)]  16 KB
  __shared__ __align__(16) float4 El4[32 * 16];  // [row][c4]        8 KB
  __shared__ __align__(16) float4 vwl4[16];      //                 256 B
  int n = blockIdx.x;
  const int bg = n & 7;
  int m = n >> 3;  // 96 = 4 bi * 3 lc * 8 dqg
  const int bi = m & 3; m >>= 2;
  const int lc = m % 3;
  const int dqg = m / 3;
  const int b = bg * 4 + bi;
  const int l0 = lc * 64, d0 = dqg * 64;
  const int tid = threadIdx.x;
  // stage F = 2^(kK*img): read coalesced by-row, write XOR-swizzled
  {
    const int l = tid >> 3, c0 = tid & 7;
#pragma unroll
    for (int k = 0; k < 2; ++k) {
      const int c = c0 + 8 * k;
      const float4 v =
          *(const float4*)(img + ((size_t)(b * kL + l0 + l)) * kD + d0 + 4 * c);
      float4 o;
      o.x = __builtin_amdgcn_exp2f(kK * v.x);
      o.y = __builtin_amdgcn_exp2f(kK * v.y);
      o.z = __builtin_amdgcn_exp2f(kK * v.z);
      o.w = __builtin_amdgcn_exp2f(kK * v.w);
      Fl4[c * 64 + (l ^ (c & 7))] = o;
    }
  }
  // stage E = 2^(kK*(x+w)) for rows 0..31 (30,31 clamp to 29; never stored)
  {
    const int row = tid >> 4, c4 = tid & 15;
    const int tc = (row < kT) ? row : kT - 1;
    const size_t gi = ((size_t)(b * kT + tc)) * kD + d0 + 4 * c4;
    const float4 xv = *(const float4*)(x + gi);
    const float4 wv4 = *(const float4*)(w + gi);
    float4 e;
    e.x = __builtin_amdgcn_exp2f(kK * (xv.x + wv4.x));
    e.y = __builtin_amdgcn_exp2f(kK * (xv.y + wv4.y));
    e.z = __builtin_amdgcn_exp2f(kK * (xv.z + wv4.z));
    e.w = __builtin_amdgcn_exp2f(kK * (xv.w + wv4.w));
    El4[row * 16 + c4] = e;
  }
  if (tid < 16) vwl4[tid] = *(const float4*)(vw + d0 + 4 * tid);
  __syncthreads();
  const int lane = tid & 63, wva = tid >> 6;  // wave owns rows r0..r0+3
  const int r0 = wva * 4;
  const float4* Ew = &El4[r0 * 16];
  float a0 = 0.f, a1 = 0.f, a2 = 0.f, a3 = 0.f;
#pragma unroll
  for (int s = 0; s < 16; ++s) {
    const float4 f = Fl4[s * 64 + (lane ^ (s & 7))];  // per-lane, swizzled
    const float4 vv = vwl4[s];                        // uniform broadcast
    const float4 E0 = Ew[s];                          // uniform broadcast
    const float4 E1 = Ew[16 + s];
    const float4 E2 = Ew[32 + s];
    const float4 E3 = Ew[48 + s];
    PAIR(E0.x, E0.y, f.x, f.y, vv.x, vv.y, a0);
    PAIR(E0.z, E0.w, f.z, f.w, vv.z, vv.w, a0);
    PAIR(E1.x, E1.y, f.x, f.y, vv.x, vv.y, a1);
    PAIR(E1.z, E1.w, f.z, f.w, vv.z, vv.w, a1);
    PAIR(E2.x, E2.y, f.x, f.y, vv.x, vv.y, a2);
    PAIR(E2.z, E2.w, f.z, f.w, vv.z, vv.w, a2);
    PAIR(E3.x, E3.y, f.x, f.y, vv.x, vv.y, a3);
    PAIR(E3.z, E3.w, f.z, f.w, vv.z, vv.w, a3);
  }
  float* gp =
      g8 + (size_t)dqg * kGsz + ((size_t)(b * kT + r0)) * kL + l0 + lane;
  gp[0] = a0;                           // t = r0   (<= 28, always valid)
  gp[kL] = a1;                          // t = r0+1 (<= 29, always valid)
  if (r0 + 2 < kT) gp[2 * kL] = a2;
  if (r0 + 3 < kT) gp[3 * kL] = a3;
}

// Fused softmax + context. 512 blocks (bg:8 x bi:4 x tgi:8 x dh:2) x 256 thr.
// Phase 1: wave wva = one t row (t = tgi*4+wva): tail l=192..195 inline
// (E recomputed from x+w), q-sum of 8 partials, softmax -> AL[l][wva].
// Phase 2: thread = d column, 4 t-accumulators, 8-deep img dbuf.
__global__ __launch_bounds__(256) void k_actx(const float* __restrict__ x,
                                              const float* __restrict__ w,
                                              const float* __restrict__ img,
                                              const float* __restrict__ vw,
                                              const float* __restrict__ g8,
                                              float* __restrict__ out) {
  __shared__ __align__(16) float AL[kL][4];
  int n = blockIdx.x;
  const int bg = n & 7;
  int m = n >> 3;  // 64 = 4 bi * 8 tgi * 2 dh
  const int bi = m & 3; m >>= 2;
  const int tgi = m & 7;
  const int dh = m >> 3;
  const int b = bg * 4 + bi;
  const int t0 = tgi * 4, d0 = dh * 256;
  const int tid = threadIdx.x;
  const int lane = tid & 63, wva = tid >> 6;
  const int t = t0 + wva;
  if (t < kT) {  // wave-uniform; dead waves (tgi=7, wva>=2) skip to barrier
    const int l4 = lane & 3, dc = lane >> 2;
    const float* ir = img + ((size_t)(b * kL + 192 + l4)) * kD + dc * 32;
    const float* xr = x + ((size_t)(b * kT + t)) * kD + dc * 32;
    const float* wr = w + ((size_t)(b * kT + t)) * kD + dc * 32;
    const float* vr = vw + dc * 32;
    float tg = 0.f;
#pragma unroll
    for (int k = 0; k < 8; ++k) {
      const float4 iv = *(const float4*)(ir + 4 * k);
      const float4 xv = *(const float4*)(xr + 4 * k);
      const float4 wv4 = *(const float4*)(wr + 4 * k);
      const float4 vv = *(const float4*)(vr + 4 * k);
      const float fx = __builtin_amdgcn_exp2f(kK * iv.x);
      const float fy = __builtin_amdgcn_exp2f(kK * iv.y);
      const float fz = __builtin_amdgcn_exp2f(kK * iv.z);
      const float fw = __builtin_amdgcn_exp2f(kK * iv.w);
      const float ex = __builtin_amdgcn_exp2f(kK * (xv.x + wv4.x));
      const float ey = __builtin_amdgcn_exp2f(kK * (xv.y + wv4.y));
      const float ez = __builtin_amdgcn_exp2f(kK * (xv.z + wv4.z));
      const float ew = __builtin_amdgcn_exp2f(kK * (xv.w + wv4.w));
      PAIR(ex, ey, fx, fy, vv.x, vv.y, tg);
      PAIR(ez, ew, fz, fw, vv.z, vv.w, tg);
    }
#pragma unroll
    for (int mm = 4; mm < 64; mm <<= 1) tg += __shfl_xor(tg, mm, 64);
    const size_t base = ((size_t)(b * kT + t)) * kL;
    float q0 = 0.f, q1 = 0.f, q2 = 0.f;
#pragma unroll
    for (int p = 0; p < 8; ++p) {
      const float* gp = g8 + (size_t)p * kGsz + base;
      q0 += gp[lane];
      q1 += gp[lane + 64];
      q2 += gp[lane + 128];
    }
    q0 *= kK; q1 *= kK; q2 *= kK;
    float q3 = (lane < 4) ? tg * kK : __builtin_inff();
    float mn = fminf(fminf(q0, q1), fminf(q2, q3));
#pragma unroll
    for (int mm = 1; mm < 64; mm <<= 1) mn = fminf(mn, __shfl_xor(mn, mm, 64));
    const float e0 = __builtin_amdgcn_exp2f(mn - q0);
    const float e1 = __builtin_amdgcn_exp2f(mn - q1);
    const float e2 = __builtin_amdgcn_exp2f(mn - q2);
    const float e3 = (lane < 4) ? __builtin_amdgcn_exp2f(mn - q3) : 0.f;
    float s = e0 + e1 + e2 + e3;
#pragma unroll
    for (int mm = 1; mm < 64; mm <<= 1) s += __shfl_xor(s, mm, 64);
    const float rs = __builtin_amdgcn_rcpf(s);
    AL[lane][wva] = e0 * rs;
    AL[lane + 64][wva] = e1 * rs;
    AL[lane + 128][wva] = e2 * rs;
    if (lane < 4) AL[lane + 192][wva] = e3 * rs;
  }
  __syncthreads();
  // ---- phase 2: context GEMV; thread = one d column ----
  const int d = d0 + tid;
  const float* ip = img + (size_t)b * kL * kD + d;
  float ac0 = 0.f, ac1 = 0.f, ac2 = 0.f, ac3 = 0.f;
  float fA[8], fB[8];
  auto loadI = [&](float* f, int bb) {
#pragma unroll
    for (int j = 0; j < 8; ++j) f[j] = ip[(size_t)(bb * 8 + j) * kD];
  };
  auto compI = [&](const float* f, int bb) {
#pragma unroll
    for (int j = 0; j < 8; ++j) {
      const int l = bb * 8 + j;
      const float4 a = *(const float4*)&AL[l][0];  // uniform broadcast
      ac0 = fmaf(f[j], a.x, ac0);
      ac1 = fmaf(f[j], a.y, ac1);
      ac2 = fmaf(f[j], a.z, ac2);
      ac3 = fmaf(f[j], a.w, ac3);
    }
  };
  loadI(fA, 0);
#pragma unroll
  for (int bb = 0; bb < 24; ++bb) {
    if (bb + 1 < 24) {
      if ((bb + 1) & 1) loadI(fB, bb + 1);
      else loadI(fA, bb + 1);
    }
    if (bb & 1) compI(fB, bb);
    else compI(fA, bb);
  }
#pragma unroll
  for (int l = 192; l < 196; ++l) {
    const float v2 = ip[(size_t)l * kD];
    const float4 a = *(const float4*)&AL[l][0];
    ac0 = fmaf(v2, a.x, ac0);
    ac1 = fmaf(v2, a.y, ac1);
    ac2 = fmaf(v2, a.z, ac2);
    ac3 = fmaf(v2, a.w, ac3);
  }
  float* op = out + ((size_t)(b * kT + t0)) * kD + d;
  op[0] = ac0;          // t0   <= 28
  op[kD] = ac1;         // t0+1 <= 29
  if (t0 + 2 < kT) op[2 * kD] = ac2;
  if (t0 + 3 < kT) op[3 * kD] = ac3;
}
}  // namespace

extern "C" void kernel_launch(void* const* d_in, const int* in_sizes, int n_in,
                              void* d_out, int out_size, void* d_ws, size_t ws_size,
                              hipStream_t stream) {
  const float* x = (const float*)d_in[0];
  const float* wordemb = (const float*)d_in[1];
  const float* img = (const float*)d_in[2];
  const float* vw = (const float*)d_in[3];
  // v_b (d_in[4]) cancels in the softmax along with sum(v_w) — unused by design.
  float* out = (float*)d_out;
  float* g8 = (float*)d_ws;  // 8 * 188,160 floats = 6.02 MB
  hipLaunchKernelGGL(k_score, dim3(768), dim3(512), 0, stream, x, wordemb, img,
                     vw, g8);
  hipLaunchKernelGGL(k_actx, dim3(512), dim3(256), 0, stream, x, wordemb, img,
                     vw, g8, out);
}

// Round 13
// 33.478 us; speedup vs baseline: 11.5068x; 2.5988x over previous
//
#include <hip/hip_runtime.h>

namespace {
constexpr int kB = 32, kT = 30, kD = 512, kL = 196;
constexpr float kK = 2.8853900817779268f;  // 2*log2(e)
constexpr size_t kGsz = (size_t)kB * kT * kL;  // 188,160

// vwi/u + vwj/v = (vwi*v + vwj*u) * rcp(u*v): 1 rcp per 2 elements
#define PAIR(ex, ey, fx, fy, vx, vy, acc)                                   \
  {                                                                         \
    const float u_ = fmaf(ex, fx, 1.f);                                     \
    const float v_ = fmaf(ey, fy, 1.f);                                     \
    acc = fmaf(fmaf(v_, vx, u_ * vy), __builtin_amdgcn_rcpf(u_ * v_), acc); \
  }

// g8[dqg][b][t][l] (l<192) = sum over 64 d of vw_d/(1+E*F).
// 768 blocks (bg:8 XCD-affine x bi:4 x lc:3 x dqg:8) x 512 thr (8 waves).
// E,F,vw staged in LDS once; inner loop: E/vw uniform broadcasts,
// F per-lane b128 (XOR-swizzled, conflict-free). No s_loads on hot path.
__global__ __launch_bounds__(512) void k_score(const float* __restrict__ x,
                                               const float* __restrict__ w,
                                               const float* __restrict__ img,
                                               const float* __restrict__ vw,
                                               float* __restrict__ g8) {
  __shared__ __align__(16) float4 Fl4[16 * 64];  // [c][l ^ (c&7)]  16 KB
  __shared__ __align__(16) float4 El4[32 * 16];  // [row][c4]        8 KB
  __shared__ __align__(16) float4 vwl4[16];      //                 256 B
  int n = blockIdx.x;
  const int bg = n & 7;
  int m = n >> 3;  // 96 = 4 bi * 3 lc * 8 dqg
  const int bi = m & 3; m >>= 2;
  const int lc = m % 3;
  const int dqg = m / 3;
  const int b = bg * 4 + bi;
  const int l0 = lc * 64, d0 = dqg * 64;
  const int tid = threadIdx.x;
  // stage F = 2^(kK*img): read coalesced by-row, write XOR-swizzled
  {
    const int l = tid >> 3, c0 = tid & 7;
#pragma unroll
    for (int k = 0; k < 2; ++k) {
      const int c = c0 + 8 * k;
      const float4 v =
          *(const float4*)(img + ((size_t)(b * kL + l0 + l)) * kD + d0 + 4 * c);
      float4 o;
      o.x = __builtin_amdgcn_exp2f(kK * v.x);
      o.y = __builtin_amdgcn_exp2f(kK * v.y);
      o.z = __builtin_amdgcn_exp2f(kK * v.z);
      o.w = __builtin_amdgcn_exp2f(kK * v.w);
      Fl4[c * 64 + (l ^ (c & 7))] = o;
    }
  }
  // stage E = 2^(kK*(x+w)) for rows 0..31 (30,31 clamp to 29; never stored)
  {
    const int row = tid >> 4, c4 = tid & 15;
    const int tc = (row < kT) ? row : kT - 1;
    const size_t gi = ((size_t)(b * kT + tc)) * kD + d0 + 4 * c4;
    const float4 xv = *(const float4*)(x + gi);
    const float4 wv4 = *(const float4*)(w + gi);
    float4 e;
    e.x = __builtin_amdgcn_exp2f(kK * (xv.x + wv4.x));
    e.y = __builtin_amdgcn_exp2f(kK * (xv.y + wv4.y));
    e.z = __builtin_amdgcn_exp2f(kK * (xv.z + wv4.z));
    e.w = __builtin_amdgcn_exp2f(kK * (xv.w + wv4.w));
    El4[row * 16 + c4] = e;
  }
  if (tid < 16) vwl4[tid] = *(const float4*)(vw + d0 + 4 * tid);
  __syncthreads();
  const int lane = tid & 63, wva = tid >> 6;  // wave owns rows r0..r0+3
  const int r0 = wva * 4;
  const float4* Ew = &El4[r0 * 16];
  float a0 = 0.f, a1 = 0.f, a2 = 0.f, a3 = 0.f;
#pragma unroll
  for (int s = 0; s < 16; ++s) {
    const float4 f = Fl4[s * 64 + (lane ^ (s & 7))];  // per-lane, swizzled
    const float4 vv = vwl4[s];                        // uniform broadcast
    const float4 E0 = Ew[s];                          // uniform broadcast
    const float4 E1 = Ew[16 + s];
    const float4 E2 = Ew[32 + s];
    const float4 E3 = Ew[48 + s];
    PAIR(E0.x, E0.y, f.x, f.y, vv.x, vv.y, a0);
    PAIR(E0.z, E0.w, f.z, f.w, vv.z, vv.w, a0);
    PAIR(E1.x, E1.y, f.x, f.y, vv.x, vv.y, a1);
    PAIR(E1.z, E1.w, f.z, f.w, vv.z, vv.w, a1);
    PAIR(E2.x, E2.y, f.x, f.y, vv.x, vv.y, a2);
    PAIR(E2.z, E2.w, f.z, f.w, vv.z, vv.w, a2);
    PAIR(E3.x, E3.y, f.x, f.y, vv.x, vv.y, a3);
    PAIR(E3.z, E3.w, f.z, f.w, vv.z, vv.w, a3);
  }
  float* gp =
      g8 + (size_t)dqg * kGsz + ((size_t)(b * kT + r0)) * kL + l0 + lane;
  gp[0] = a0;                           // t = r0   (<= 28)
  gp[kL] = a1;                          // t = r0+1 (<= 29)
  if (r0 + 2 < kT) gp[2 * kL] = a2;
  if (r0 + 3 < kT) gp[3 * kL] = a3;
}

// softmax over l: l<192 from 8 partials; l=192..195 inline (E from x+w).
// Measured 3.4 us in R11 instrumentation (with Eg; tail now recomputes E).
__global__ __launch_bounds__(512) void k_alpha(const float* __restrict__ g8,
                                               const float* __restrict__ x,
                                               const float* __restrict__ w,
                                               const float* __restrict__ img,
                                               const float* __restrict__ vw,
                                               float* __restrict__ alpha) {
  const int qd = blockIdx.x, b = blockIdx.y;
  const int lane = threadIdx.x & 63, wv = threadIdx.x >> 6;
  const int t = qd * 8 + wv;
  if (t >= kT) return;
  // tail: lane = (l4:4, dc:16); each lane sums 32 d for l = 192+l4
  const int l4 = lane & 3, dc = lane >> 2;
  const float* ir = img + ((size_t)(b * kL + 192 + l4)) * kD + dc * 32;
  const float* xr = x + ((size_t)(b * kT + t)) * kD + dc * 32;
  const float* wr = w + ((size_t)(b * kT + t)) * kD + dc * 32;
  const float* vr = vw + dc * 32;
  float tg = 0.f;
#pragma unroll
  for (int k = 0; k < 8; ++k) {
    const float4 iv = *(const float4*)(ir + 4 * k);
    const float4 xv = *(const float4*)(xr + 4 * k);
    const float4 wv4 = *(const float4*)(wr + 4 * k);
    const float4 vv = *(const float4*)(vr + 4 * k);
    const float fx = __builtin_amdgcn_exp2f(kK * iv.x);
    const float fy = __builtin_amdgcn_exp2f(kK * iv.y);
    const float fz = __builtin_amdgcn_exp2f(kK * iv.z);
    const float fw = __builtin_amdgcn_exp2f(kK * iv.w);
    const float ex = __builtin_amdgcn_exp2f(kK * (xv.x + wv4.x));
    const float ey = __builtin_amdgcn_exp2f(kK * (xv.y + wv4.y));
    const float ez = __builtin_amdgcn_exp2f(kK * (xv.z + wv4.z));
    const float ew = __builtin_amdgcn_exp2f(kK * (xv.w + wv4.w));
    PAIR(ex, ey, fx, fy, vv.x, vv.y, tg);
    PAIR(ez, ew, fz, fw, vv.z, vv.w, tg);
  }
#pragma unroll
  for (int mm = 4; mm < 64; mm <<= 1) tg += __shfl_xor(tg, mm, 64);
  const size_t base = ((size_t)(b * kT + t)) * kL;
  float q0 = 0.f, q1 = 0.f, q2 = 0.f;
#pragma unroll
  for (int p = 0; p < 8; ++p) {
    const float* gp = g8 + (size_t)p * kGsz + base;
    q0 += gp[lane];
    q1 += gp[lane + 64];
    q2 += gp[lane + 128];
  }
  q0 *= kK; q1 *= kK; q2 *= kK;
  float q3 = (lane < 4) ? tg * kK : __builtin_inff();
  float m = fminf(fminf(q0, q1), fminf(q2, q3));
#pragma unroll
  for (int mm = 1; mm < 64; mm <<= 1) m = fminf(m, __shfl_xor(m, mm, 64));
  const float e0 = __builtin_amdgcn_exp2f(m - q0);
  const float e1 = __builtin_amdgcn_exp2f(m - q1);
  const float e2 = __builtin_amdgcn_exp2f(m - q2);
  const float e3 = (lane < 4) ? __builtin_amdgcn_exp2f(m - q3) : 0.f;
  float s = e0 + e1 + e2 + e3;
#pragma unroll
  for (int mm = 1; mm < 64; mm <<= 1) s += __shfl_xor(s, mm, 64);
  const float rs = __builtin_amdgcn_rcpf(s);
  float* ab = alpha + base;
  ab[lane] = e0 * rs;
  ab[lane + 64] = e1 * rs;
  ab[lane + 128] = e2 * rs;
  if (lane < 4) ab[lane + 192] = e3 * rs;
}

// context[b][t][d] = sum_l img[b][l][d]*alpha[b][t][l].
// 384 blocks, XCD b-affinity; 4 waves own 49-l quarters; 8-deep img dbuf.
// R9-proven (<10us bound; never spilled).
__global__ __launch_bounds__(256) void k_ctx(const float* __restrict__ img,
                                             const float* __restrict__ alpha,
                                             float* __restrict__ out) {
  __shared__ __align__(16) float red[4][5][256];  // 20 KB
  int n = blockIdx.x;
  const int bg = n & 7;
  int m = n >> 3;  // 48 = 4 bi * 6 tg * 2 dh
  const int bi = m & 3; m >>= 2;
  const int tg = m % 6;
  const int dh = m / 6;
  const int b = bg * 4 + bi;
  const int t0 = tg * 5, d0 = dh * 256;
  const int tid = threadIdx.x;
  const int lane = tid & 63;
  const int lru = __builtin_amdgcn_readfirstlane(tid >> 6);
  const float* ap = alpha + ((size_t)(b * kT + t0)) * kL + lru * 49;  // uniform
  const float* ip = img + ((size_t)(b * kL + lru * 49)) * kD + d0 + 4 * lane;
  float4 acc[5];
#pragma unroll
  for (int j = 0; j < 5; ++j) acc[j] = {0.f, 0.f, 0.f, 0.f};
  auto loadI = [&](float4* dst, int bb) {
#pragma unroll
    for (int j = 0; j < 8; ++j)
      dst[j] = *(const float4*)(ip + (size_t)(bb * 8 + j) * kD);
  };
  auto compI = [&](const float4* f, int bb) {
#pragma unroll
    for (int j = 0; j < 8; ++j) {
      const int i = bb * 8 + j;
      const float a0 = ap[i];
      const float a1 = ap[kL + i];
      const float a2 = ap[2 * kL + i];
      const float a3 = ap[3 * kL + i];
      const float a4 = ap[4 * kL + i];
      acc[0].x = fmaf(f[j].x, a0, acc[0].x); acc[0].y = fmaf(f[j].y, a0, acc[0].y);
      acc[0].z = fmaf(f[j].z, a0, acc[0].z); acc[0].w = fmaf(f[j].w, a0, acc[0].w);
      acc[1].x = fmaf(f[j].x, a1, acc[1].x); acc[1].y = fmaf(f[j].y, a1, acc[1].y);
      acc[1].z = fmaf(f[j].z, a1, acc[1].z); acc[1].w = fmaf(f[j].w, a1, acc[1].w);
      acc[2].x = fmaf(f[j].x, a2, acc[2].x); acc[2].y = fmaf(f[j].y, a2, acc[2].y);
      acc[2].z = fmaf(f[j].z, a2, acc[2].z); acc[2].w = fmaf(f[j].w, a2, acc[2].w);
      acc[3].x = fmaf(f[j].x, a3, acc[3].x); acc[3].y = fmaf(f[j].y, a3, acc[3].y);
      acc[3].z = fmaf(f[j].z, a3, acc[3].z); acc[3].w = fmaf(f[j].w, a3, acc[3].w);
      acc[4].x = fmaf(f[j].x, a4, acc[4].x); acc[4].y = fmaf(f[j].y, a4, acc[4].y);
      acc[4].z = fmaf(f[j].z, a4, acc[4].z); acc[4].w = fmaf(f[j].w, a4, acc[4].w);
    }
  };
  float4 fA[8], fB[8];
  loadI(fA, 0);
  loadI(fB, 1); compI(fA, 0);
  loadI(fA, 2); compI(fB, 1);
  loadI(fB, 3); compI(fA, 2);
  loadI(fA, 4); compI(fB, 3);
  loadI(fB, 5); compI(fA, 4);
  compI(fB, 5);
  {  // tail l-index 48 of this quarter
    const float4 v = *(const float4*)(ip + (size_t)48 * kD);
    const int i = 48;
    const float a0 = ap[i], a1 = ap[kL + i], a2 = ap[2 * kL + i],
                a3 = ap[3 * kL + i], a4 = ap[4 * kL + i];
    acc[0].x = fmaf(v.x, a0, acc[0].x); acc[0].y = fmaf(v.y, a0, acc[0].y);
    acc[0].z = fmaf(v.z, a0, acc[0].z); acc[0].w = fmaf(v.w, a0, acc[0].w);
    acc[1].x = fmaf(v.x, a1, acc[1].x); acc[1].y = fmaf(v.y, a1, acc[1].y);
    acc[1].z = fmaf(v.z, a1, acc[1].z); acc[1].w = fmaf(v.w, a1, acc[1].w);
    acc[2].x = fmaf(v.x, a2, acc[2].x); acc[2].y = fmaf(v.y, a2, acc[2].y);
    acc[2].z = fmaf(v.z, a2, acc[2].z); acc[2].w = fmaf(v.w, a2, acc[2].w);
    acc[3].x = fmaf(v.x, a3, acc[3].x); acc[3].y = fmaf(v.y, a3, acc[3].y);
    acc[3].z = fmaf(v.z, a3, acc[3].z); acc[3].w = fmaf(v.w, a3, acc[3].w);
    acc[4].x = fmaf(v.x, a4, acc[4].x); acc[4].y = fmaf(v.y, a4, acc[4].y);
    acc[4].z = fmaf(v.z, a4, acc[4].z); acc[4].w = fmaf(v.w, a4, acc[4].w);
  }
#pragma unroll
  for (int j = 0; j < 5; ++j) *(float4*)&red[lru][j][4 * lane] = acc[j];
  __syncthreads();
#pragma unroll
  for (int j = 0; j < 5; ++j) {
    const float s =
        red[0][j][tid] + red[1][j][tid] + red[2][j][tid] + red[3][j][tid];
    out[((size_t)(b * kT + t0 + j)) * kD + d0 + tid] = s;
  }
}
}  // namespace

extern "C" void kernel_launch(void* const* d_in, const int* in_sizes, int n_in,
                              void* d_out, int out_size, void* d_ws, size_t ws_size,
                              hipStream_t stream) {
  const float* x = (const float*)d_in[0];
  const float* wordemb = (const float*)d_in[1];
  const float* img = (const float*)d_in[2];
  const float* vw = (const float*)d_in[3];
  // v_b (d_in[4]) cancels in the softmax along with sum(v_w) — unused by design.
  float* out = (float*)d_out;
  float* g8 = (float*)d_ws;        // 6.02 MB
  float* alpha = g8 + 8 * kGsz;    // 0.75 MB
  hipLaunchKernelGGL(k_score, dim3(768), dim3(512), 0, stream, x, wordemb, img,
                     vw, g8);
  hipLaunchKernelGGL(k_alpha, dim3(4, kB), dim3(512), 0, stream, g8, x, wordemb,
                     img, vw, alpha);
  hipLaunchKernelGGL(k_ctx, dim3(384), dim3(256), 0, stream, img, alpha, out);
}